// Round 2
// 227.119 us; speedup vs baseline: 1.0307x; 1.0307x over previous
//
#include <hip/hip_runtime.h>
#include <cmath>

typedef __attribute__((ext_vector_type(8))) short short8;
typedef __attribute__((ext_vector_type(4))) float floatx4;

#define T_TOK 32768
#define DIMK 512

__device__ __forceinline__ unsigned short f2bf(float f) {
  union { float f; unsigned int u; } v; v.f = f;
  unsigned int r = (v.u + 0x7fffu + ((v.u >> 16) & 1u)) >> 16;
  return (unsigned short)r;
}
__device__ __forceinline__ float bf2f(unsigned short h) {
  union { unsigned int u; float f; } v; v.u = ((unsigned int)h) << 16;
  return v.f;
}

// async global->LDS 16B per lane: HW writes lane i at ldsbase + i*16
__device__ __forceinline__ void gload_lds16(const unsigned short* g, unsigned short* ldsbase) {
  __builtin_amdgcn_global_load_lds(
      (const __attribute__((address_space(1))) unsigned int*)g,
      (__attribute__((address_space(3))) unsigned int*)ldsbase, 16, 0, 0);
}

// ------- prep: [blocks 0..2047] weights->bf16 + rope + zero; [2048..10239] rmsnorm -------
__global__ __launch_bounds__(256) void k_prep(const float* __restrict__ x,
    const float* __restrict__ norm_w, const float* __restrict__ wq,
    const float* __restrict__ wk, const float* __restrict__ wv,
    const float* __restrict__ wo, unsigned short* __restrict__ Wb,
    unsigned short* __restrict__ wob, float2* __restrict__ rope,
    float* __restrict__ KVz, unsigned short* __restrict__ xn) {
  if (blockIdx.x < 2048) {
    int i = blockIdx.x * 256 + threadIdx.x;  // 524288
    float v;
    if (i < 262144) v = wq[i];
    else if (i < 393216) v = wk[i - 262144];
    else v = wv[i - 393216];
    Wb[i] = f2bf(v);
    if (i < 262144) {
      wob[i] = f2bf(wo[i]);
      int s = i >> 5, m = i & 31;
      const double c0 = 0.74989420933245582;   // 10^(-1/8)
      double c1 = c0 * c0, c2 = c1 * c1, c3 = c2 * c2, c4 = c3 * c3;
      double p = 1.0;
      if (m & 1)  p *= c0;
      if (m & 2)  p *= c1;
      if (m & 4)  p *= c2;
      if (m & 8)  p *= c3;
      if (m & 16) p *= c4;
      double ang = (double)s * p;
      const double TWO_PI = 6.2831853071795864769;
      double q = rint(ang * (1.0 / TWO_PI));
      double r = fma(-q, TWO_PI, ang);
      float rf = (float)r;
      rope[i] = make_float2(cosf(rf), sinf(rf));
    }
    if (i < 2048) KVz[i] = 0.f;
  } else {
    int bid = blockIdx.x - 2048;
    int wave = threadIdx.x >> 6, lane = threadIdx.x & 63;
    size_t t = (size_t)bid * 4 + wave;
    const float4* xr = (const float4*)(x + t * DIMK);
    float4 a = xr[lane * 2];
    float4 b = xr[lane * 2 + 1];
    float ss = a.x * a.x + a.y * a.y + a.z * a.z + a.w * a.w
             + b.x * b.x + b.y * b.y + b.z * b.z + b.w * b.w;
    #pragma unroll
    for (int off = 32; off >= 1; off >>= 1) ss += __shfl_xor(ss, off, 64);
    float scale = rsqrtf(ss * (1.0f / DIMK) + 1e-6f);
    const float4* wr = (const float4*)norm_w;
    float4 w0 = wr[lane * 2], w1 = wr[lane * 2 + 1];
    uint4 o;
    o.x = (unsigned int)f2bf(a.x * scale * w0.x) | ((unsigned int)f2bf(a.y * scale * w0.y) << 16);
    o.y = (unsigned int)f2bf(a.z * scale * w0.z) | ((unsigned int)f2bf(a.w * scale * w0.w) << 16);
    o.z = (unsigned int)f2bf(b.x * scale * w1.x) | ((unsigned int)f2bf(b.y * scale * w1.y) << 16);
    o.w = (unsigned int)f2bf(b.z * scale * w1.z) | ((unsigned int)f2bf(b.w * scale * w1.w) << 16);
    *(uint4*)(xn + t * DIMK + lane * 8) = o;
  }
}

// ------- GEMM: C(M,N) = A(M,512) * Bw(N,512)^T -------
// 256x256 tile, BK=64, 8 waves (2Mx4N), 128KiB LDS double-buffer, 8-phase schedule
// (T3+T4: counted vmcnt(8), never 0 in main loop) + setprio around MFMA (T5).
// LDS XOR-swizzle identical to the verified 128-tile kernel (0 bank conflicts):
// LDS[R][cb] = global[R][cb ^ (R&7)], staged via pre-swizzled global source.
//
// Read sets per K-tile pair (kt->buf0, kt+1->buf1):
//   A-buf0: P1 (ah0: rows 0-63,128-191), P3 (ah1: rows 64-127,192-255)  -> done end-P3
//   B-buf0: P1 (bh0), P2 (bh1)                                          -> done end-P2
//   A-buf1: P5 (ah0), P7 (ah1)                                          -> done end-P7
//   B-buf1: P5 (bh0), P6 (bh1)                                          -> done end-P6
// Stage rotation (each stage strictly after last read of its slot):
//   P3: B-buf0(kt+2) full   P4: A-buf0(kt+2) full
//   P7: B-buf1(kt+3) full   P8: A-buf1(kt+3) full
// vmcnt(8) at end-P4 (prev P7/P8 = buf1 kt+1 landed before P5) and at
// end-P8 (this P3/P4 = buf0 kt+2 landed before next P1). In-order retire.
template <bool BF16_OUT>
__global__ __launch_bounds__(512, 2) void k_gemm256(const unsigned short* __restrict__ A,
    const unsigned short* __restrict__ Bw, void* __restrict__ Cv, int N) {
  constexpr int K = DIMK;
  extern __shared__ __align__(16) unsigned short smem[];
  unsigned short* const AsP = smem;            // [2][16384] shorts (64 KiB)
  unsigned short* const BsP = smem + 32768;    // [2][16384] shorts (64 KiB)

  const int tid = threadIdx.x;
  const int wave = tid >> 6, lane = tid & 63;
  const int r = lane & 15, quad = lane >> 4, r7 = r & 7;
  const int wm = (wave >> 2) * 128, wn = (wave & 3) * 64;

  // XCD-aware bijective swizzle: each XCD gets contiguous logical tiles
  const int nwg = gridDim.x * gridDim.y;
  const int bid = blockIdx.x + gridDim.x * blockIdx.y;
  const int cpx = nwg >> 3;
  const int nid = (bid & 7) * cpx + (bid >> 3);
  const int m0 = (nid & 127) * 256;   // gridDim.x == 128 always here
  const int n0 = (nid >> 7) * 256;

  // staging source (pre-swizzled): lane covers row (lane>>3), col-block (lane&7)^(row&7)
  const int srow = lane >> 3;
  const int scb = (lane & 7) ^ srow;
  const unsigned short* const Asrc = A + (size_t)(m0 + wave * 8 + srow) * K + scb * 8;
  const unsigned short* const Bsrc = Bw + (size_t)(n0 + wave * 8 + srow) * K + scb * 8;
  unsigned short* const Adst = AsP + wave * 8 * 64;  // + buf*16384 + rowoff*64
  unsigned short* const Bdst = BsP + wave * 8 * 64;

#define STAGE_A(buf, h, kt) do { \
    gload_lds16(Asrc + (size_t)((h) * 128) * K + (kt) * 64, Adst + (buf) * 16384 + ((h) * 128) * 64); \
    gload_lds16(Asrc + (size_t)((h) * 128 + 64) * K + (kt) * 64, Adst + (buf) * 16384 + ((h) * 128 + 64) * 64); \
  } while (0)
#define STAGE_B(buf, h, kt) do { \
    gload_lds16(Bsrc + (size_t)((h) * 128) * K + (kt) * 64, Bdst + (buf) * 16384 + ((h) * 128) * 64); \
    gload_lds16(Bsrc + (size_t)((h) * 128 + 64) * K + (kt) * 64, Bdst + (buf) * 16384 + ((h) * 128 + 64) * 64); \
  } while (0)

  short8 af[4][2], b0[2][2], b1[2][2];
  floatx4 acc[8][4];
  #pragma unroll
  for (int i = 0; i < 8; i++)
    #pragma unroll
    for (int j = 0; j < 4; j++)
      acc[i][j] = (floatx4){0.f, 0.f, 0.f, 0.f};

#define LDA8(buf, ah) do { \
    _Pragma("unroll") for (int ii = 0; ii < 4; ii++) \
      _Pragma("unroll") for (int kk = 0; kk < 2; kk++) \
        af[ii][kk] = *(const short8*)&AsP[(buf) * 16384 + (wm + (ah) * 64 + ii * 16 + r) * 64 + ((kk * 4 + quad) ^ r7) * 8]; \
  } while (0)
#define LDB4(buf, bh, arr) do { \
    _Pragma("unroll") for (int jj = 0; jj < 2; jj++) \
      _Pragma("unroll") for (int kk = 0; kk < 2; kk++) \
        arr[jj][kk] = *(const short8*)&BsP[(buf) * 16384 + (wn + (bh) * 32 + jj * 16 + r) * 64 + ((kk * 4 + quad) ^ r7) * 8]; \
  } while (0)
#define MFMAQ(ah, bh, arr) do { \
    __builtin_amdgcn_s_setprio(1); \
    _Pragma("unroll") for (int ii = 0; ii < 4; ii++) \
      _Pragma("unroll") for (int jj = 0; jj < 2; jj++) \
        _Pragma("unroll") for (int kk = 0; kk < 2; kk++) \
          acc[(ah) * 4 + ii][(bh) * 2 + jj] = __builtin_amdgcn_mfma_f32_16x16x32_bf16( \
              af[ii][kk], arr[jj][kk], acc[(ah) * 4 + ii][(bh) * 2 + jj], 0, 0, 0); \
    __builtin_amdgcn_s_setprio(0); \
  } while (0)
#define BAR() do { asm volatile("" ::: "memory"); __builtin_amdgcn_s_barrier(); asm volatile("" ::: "memory"); } while (0)
#define VMW(n) do { asm volatile("s_waitcnt vmcnt(" #n ")" ::: "memory"); __builtin_amdgcn_sched_barrier(0); } while (0)

  // ---- prologue: kt0 -> buf0 (8 loads), kt1 -> buf1 (8 loads); wait for kt0
  STAGE_A(0, 0, 0); STAGE_B(0, 0, 0); STAGE_A(0, 1, 0); STAGE_B(0, 1, 0);
  STAGE_A(1, 0, 1); STAGE_B(1, 0, 1); STAGE_A(1, 1, 1); STAGE_B(1, 1, 1);
  VMW(8);
  BAR();

  // ---- main: iterations over K-tile pairs (kt, kt+1); kt even->buf0, odd->buf1
  #pragma unroll
  for (int it = 0; it < 3; ++it) {
    const int kt = it * 2;
    // P1: quadrant (Ah0,Bh0) of kt
    LDA8(0, 0); LDB4(0, 0, b0);
    BAR(); MFMAQ(0, 0, b0); BAR();
    // P2: (Ah0,Bh1)
    LDB4(0, 1, b1);
    BAR(); MFMAQ(0, 1, b1); BAR();
    // P3: (Ah1,Bh1); B-buf0 fully read -> stage B-buf0(kt+2)
    LDA8(0, 1); STAGE_B(0, 0, kt + 2); STAGE_B(0, 1, kt + 2);
    BAR(); MFMAQ(1, 1, b1); BAR();
    // P4: (Ah1,Bh0) regs-only; A-buf0 fully read -> stage A-buf0(kt+2)
    STAGE_A(0, 0, kt + 2); STAGE_A(0, 1, kt + 2);
    BAR(); MFMAQ(1, 0, b0); VMW(8); BAR();
    // P5: quadrant (Ah0,Bh0) of kt+1
    LDA8(1, 0); LDB4(1, 0, b0);
    BAR(); MFMAQ(0, 0, b0); BAR();
    // P6
    LDB4(1, 1, b1);
    BAR(); MFMAQ(0, 1, b1); BAR();
    // P7: B-buf1 fully read -> stage B-buf1(kt+3)
    LDA8(1, 1); STAGE_B(1, 0, kt + 3); STAGE_B(1, 1, kt + 3);
    BAR(); MFMAQ(1, 1, b1); BAR();
    // P8: A-buf1 fully read -> stage A-buf1(kt+3)
    STAGE_A(1, 0, kt + 3); STAGE_A(1, 1, kt + 3);
    BAR(); MFMAQ(1, 0, b0); VMW(8); BAR();
  }

  // ---- epilogue: kt=6 (buf0), kt=7 (buf1); nothing left to stage
  LDA8(0, 0); LDB4(0, 0, b0);
  BAR(); MFMAQ(0, 0, b0); BAR();
  LDB4(0, 1, b1);
  BAR(); MFMAQ(0, 1, b1); BAR();
  LDA8(0, 1);
  BAR(); MFMAQ(1, 1, b1); BAR();
  MFMAQ(1, 0, b0); VMW(0); BAR();
  LDA8(1, 0); LDB4(1, 0, b0);
  BAR(); MFMAQ(0, 0, b0); BAR();
  LDB4(1, 1, b1);
  BAR(); MFMAQ(0, 1, b1); BAR();
  LDA8(1, 1);
  BAR(); MFMAQ(1, 1, b1); BAR();
  MFMAQ(1, 0, b0);

  // ---- C write. C/D layout: col = lane&15, row = quad*4 + p
  #pragma unroll
  for (int i = 0; i < 8; i++)
    #pragma unroll
    for (int j = 0; j < 4; j++) {
      int row = m0 + wm + i * 16 + quad * 4;
      int col = n0 + wn + j * 16 + r;
      #pragma unroll
      for (int p = 0; p < 4; p++) {
        if constexpr (BF16_OUT) {
          ((unsigned short*)Cv)[(size_t)(row + p) * N + col] = f2bf(acc[i][j][p]);
        } else {
          ((float*)Cv)[(size_t)(row + p) * N + col] = acc[i][j][p];
        }
      }
    }
#undef STAGE_A
#undef STAGE_B
#undef LDA8
#undef LDB4
#undef MFMAQ
#undef BAR
#undef VMW
}

// ------- KV / Ksum reduction over sequence -------
__global__ __launch_bounds__(256) void k_kvred(const unsigned short* __restrict__ qkv,
    const float2* __restrict__ rope, float* __restrict__ KV, float* __restrict__ Ksum) {
  int bk = blockIdx.y;
  int b = bk >> 2, kh = bk & 3;
  int tid = threadIdx.x;
  int m = tid & 31;
  int sl = tid >> 5;
  int s0 = blockIdx.x * 256;
  float kvr = 0.f, kvi = 0.f, ksr = 0.f, ksi = 0.f;
  for (int si = sl; si < 256; si += 8) {
    int s = s0 + si;
    size_t t = (size_t)b * 8192 + s;
    const unsigned short* base = qkv + t * 1024;
    unsigned int kp = *(const unsigned int*)(base + 512 + kh * 64 + 2 * m);
    unsigned int vp = *(const unsigned int*)(base + 768 + kh * 64 + 2 * m);
    float kx = bf2f((unsigned short)(kp & 0xffffu));
    float ky = bf2f((unsigned short)(kp >> 16));
    float vx = bf2f((unsigned short)(vp & 0xffffu));
    float vy = bf2f((unsigned short)(vp >> 16));
    float2 cs = rope[s * 32 + m];
    float kr = kx * cs.x - ky * cs.y;
    float ki = kx * cs.y + ky * cs.x;
    kr = kr > 0.f ? kr + 1.f : __expf(kr);
    ki = ki > 0.f ? ki + 1.f : __expf(ki);
    kvr += kr * vx; kvi += ki * vy;
    ksr += kr;      ksi += ki;
  }
  __shared__ float red[256 * 4];
  red[tid * 4 + 0] = kvr; red[tid * 4 + 1] = kvi;
  red[tid * 4 + 2] = ksr; red[tid * 4 + 3] = ksi;
  __syncthreads();
  if (sl == 0) {
    for (int q = 1; q < 8; q++) {
      kvr += red[(q * 32 + m) * 4 + 0]; kvi += red[(q * 32 + m) * 4 + 1];
      ksr += red[(q * 32 + m) * 4 + 2]; ksi += red[(q * 32 + m) * 4 + 3];
    }
    atomicAdd(&KV[bk * 64 + 2 * m], kvr);
    atomicAdd(&KV[bk * 64 + 2 * m + 1], kvi);
    atomicAdd(&Ksum[bk * 64 + 2 * m], ksr);
    atomicAdd(&Ksum[bk * 64 + 2 * m + 1], ksi);
  }
}

// ------- Q path: half-wave (32 lanes) per head, one uint pair per lane -------
__global__ __launch_bounds__(256) void k_qkern(const unsigned short* __restrict__ qkv,
    const float2* __restrict__ rope, const float* __restrict__ KV,
    const float* __restrict__ Ksum, unsigned short* __restrict__ Yb) {
  const int h = threadIdx.x >> 5;   // head 0..7
  const int pr = threadIdx.x & 31;  // rotation pair 0..31
  for (int t = blockIdx.x; t < T_TOK; t += gridDim.x) {
    int b = t >> 13, pos = t & 8191;
    unsigned int qp = *(const unsigned int*)(qkv + (size_t)t * 1024 + h * 64 + 2 * pr);
    float qx = bf2f((unsigned short)(qp & 0xffffu));
    float qy = bf2f((unsigned short)(qp >> 16));
    float2 cs = rope[pos * 32 + pr];
    float ar = qx * cs.x - qy * cs.y;
    float ai = qx * cs.y + qy * cs.x;
    ar = ar > 0.f ? ar + 1.f : __expf(ar);
    ai = ai > 0.f ? ai + 1.f : __expf(ai);
    int bk = b * 4 + (h >> 1);
    float2 ks = *(const float2*)(Ksum + bk * 64 + 2 * pr);
    float z = ar * ks.x + ai * ks.y;
    #pragma unroll
    for (int off = 16; off >= 1; off >>= 1) z += __shfl_xor(z, off, 64);  // stays in half-wave
    float2 kv = *(const float2*)(KV + bk * 64 + 2 * pr);
    float inv = 1.0f / (z + 1e-6f);
    unsigned int o = (unsigned int)f2bf(ar * kv.x * inv)
                   | ((unsigned int)f2bf(ai * kv.y * inv) << 16);
    *(unsigned int*)(Yb + (size_t)t * 512 + h * 64 + 2 * pr) = o;
  }
}

extern "C" void kernel_launch(void* const* d_in, const int* in_sizes, int n_in,
                              void* d_out, int out_size, void* d_ws, size_t ws_size,
                              hipStream_t stream) {
  const float* x = (const float*)d_in[0];
  const float* norm_w = (const float*)d_in[1];
  const float* wq = (const float*)d_in[2];
  const float* wk = (const float*)d_in[3];
  const float* wv = (const float*)d_in[4];
  const float* wo = (const float*)d_in[5];
  float* out = (float*)d_out;

  char* ws = (char*)d_ws;
  unsigned short* xn  = (unsigned short*)(ws);                  // 33,554,432 B
  unsigned short* Wb  = (unsigned short*)(ws + 33554432);       //  1,048,576 B
  unsigned short* wob = (unsigned short*)(ws + 34603008);       //    524,288 B
  unsigned short* qkv = (unsigned short*)(ws + 35127296);       // 67,108,864 B
  float2* rope        = (float2*)(ws + 102236160);              //  2,097,152 B
  float* KV           = (float*)(ws + 104333312);               //      4,096 B
  float* Ksum         = (float*)(ws + 104337408);               //      4,096 B
  unsigned short* Yb  = (unsigned short*)(ws + 104341504);      // 33,554,432 B

  static bool s_attr = false;
  if (!s_attr) {
    (void)hipFuncSetAttribute(reinterpret_cast<const void*>(&k_gemm256<true>),
                              hipFuncAttributeMaxDynamicSharedMemorySize, 131072);
    (void)hipFuncSetAttribute(reinterpret_cast<const void*>(&k_gemm256<false>),
                              hipFuncAttributeMaxDynamicSharedMemorySize, 131072);
    s_attr = true;
  }

  k_prep<<<10240, 256, 0, stream>>>(x, norm_w, wq, wk, wv, wo, Wb, wob, rope, KV, xn);
  k_gemm256<true><<<dim3(128, 4), 512, 131072, stream>>>(xn, Wb, (void*)qkv, 1024);
  k_kvred<<<dim3(32, 16), 256, 0, stream>>>(qkv, rope, KV, Ksum);
  k_qkern<<<4096, 256, 0, stream>>>(qkv, rope, KV, Ksum, Yb);
  k_gemm256<false><<<dim3(128, 2), 512, 131072, stream>>>(Yb, wob, (void*)out, 512);
}

// Round 4
// 220.304 us; speedup vs baseline: 1.0626x; 1.0309x over previous
//
#include <hip/hip_runtime.h>
#include <cmath>

typedef __attribute__((ext_vector_type(8))) short short8;
typedef __attribute__((ext_vector_type(4))) float floatx4;

#define T_TOK 32768
#define DIMK 512

__device__ __forceinline__ unsigned short f2bf(float f) {
  union { float f; unsigned int u; } v; v.f = f;
  unsigned int r = (v.u + 0x7fffu + ((v.u >> 16) & 1u)) >> 16;
  return (unsigned short)r;
}
__device__ __forceinline__ float bf2f(unsigned short h) {
  union { unsigned int u; float f; } v; v.u = ((unsigned int)h) << 16;
  return v.f;
}

// async global->LDS 16B per lane: HW writes lane i at ldsbase + i*16
__device__ __forceinline__ void gload_lds16(const unsigned short* g, unsigned short* ldsbase) {
  __builtin_amdgcn_global_load_lds(
      (const __attribute__((address_space(1))) unsigned int*)g,
      (__attribute__((address_space(3))) unsigned int*)ldsbase, 16, 0, 0);
}

// ------- prep: [blocks 0..2047] weights->bf16 + rope + zero; [2048..10239] rmsnorm -------
// Wb row layout: rows 0..511 = wq rows. Rows 512..1023 INTERLEAVED per KV head:
//   row 512 + h*128 + d       <- wk row h*64+d   (K dims of head h)
//   row 512 + h*128 + 64 + d  <- wv row h*64+d   (V dims of head h)
// so a 256-wide GEMM n-tile at n0 in {512,768} holds matched K,V for 2 heads.
__global__ __launch_bounds__(256) void k_prep(const float* __restrict__ x,
    const float* __restrict__ norm_w, const float* __restrict__ wq,
    const float* __restrict__ wk, const float* __restrict__ wv,
    const float* __restrict__ wo, unsigned short* __restrict__ Wb,
    unsigned short* __restrict__ wob, float2* __restrict__ rope,
    float* __restrict__ KVz, unsigned short* __restrict__ xn) {
  if (blockIdx.x < 2048) {
    int i = blockIdx.x * 256 + threadIdx.x;  // 524288
    float v;
    if (i < 262144) {
      v = wq[i];
    } else {
      int R = i >> 9, col = i & 511;
      int h = (R - 512) >> 7, rem = (R - 512) & 127;
      if (rem < 64) v = wk[(h * 64 + rem) * 512 + col];
      else          v = wv[(h * 64 + rem - 64) * 512 + col];
    }
    Wb[i] = f2bf(v);
    if (i < 262144) {
      wob[i] = f2bf(wo[i]);
      int s = i >> 5, m = i & 31;
      const double c0 = 0.74989420933245582;   // 10^(-1/8)
      double c1 = c0 * c0, c2 = c1 * c1, c3 = c2 * c2, c4 = c3 * c3;
      double p = 1.0;
      if (m & 1)  p *= c0;
      if (m & 2)  p *= c1;
      if (m & 4)  p *= c2;
      if (m & 8)  p *= c3;
      if (m & 16) p *= c4;
      double ang = (double)s * p;
      const double TWO_PI = 6.2831853071795864769;
      double q = rint(ang * (1.0 / TWO_PI));
      double r = fma(-q, TWO_PI, ang);
      float rf = (float)r;
      rope[i] = make_float2(cosf(rf), sinf(rf));
    }
    if (i < 2048) KVz[i] = 0.f;   // zero KV (1024 f32) + Ksum (1024 f32)
  } else {
    int bid = blockIdx.x - 2048;
    int wave = threadIdx.x >> 6, lane = threadIdx.x & 63;
    size_t t = (size_t)bid * 4 + wave;
    const float4* xr = (const float4*)(x + t * DIMK);
    float4 a = xr[lane * 2];
    float4 b = xr[lane * 2 + 1];
    float ss = a.x * a.x + a.y * a.y + a.z * a.z + a.w * a.w
             + b.x * b.x + b.y * b.y + b.z * b.z + b.w * b.w;
    #pragma unroll
    for (int off = 32; off >= 1; off >>= 1) ss += __shfl_xor(ss, off, 64);
    float scale = rsqrtf(ss * (1.0f / DIMK) + 1e-6f);
    const float4* wr = (const float4*)norm_w;
    float4 w0 = wr[lane * 2], w1 = wr[lane * 2 + 1];
    uint4 o;
    o.x = (unsigned int)f2bf(a.x * scale * w0.x) | ((unsigned int)f2bf(a.y * scale * w0.y) << 16);
    o.y = (unsigned int)f2bf(a.z * scale * w0.z) | ((unsigned int)f2bf(a.w * scale * w0.w) << 16);
    o.z = (unsigned int)f2bf(b.x * scale * w1.x) | ((unsigned int)f2bf(b.y * scale * w1.y) << 16);
    o.w = (unsigned int)f2bf(b.z * scale * w1.z) | ((unsigned int)f2bf(b.w * scale * w1.w) << 16);
    *(uint4*)(xn + t * DIMK + lane * 8) = o;
  }
}

// ------- GEMM: C(M,N) = A(M,512) * Bw(N,512)^T -------
// 256x256 tile, BK=64, 8 waves, 8-phase counted-vmcnt schedule (verified r2).
//  * XCD remap for A-reuse: XCD x owns m-tiles [16x,16x+16) x ALL n-tiles,
//    n fastest in dispatch order -> consecutive blocks on an XCD share an
//    A-tile (L2-hot), cutting A L2-fill to ~1x.
//  * FUSE: for n0>=512 tiles (interleaved K|V columns), the epilogue computes
//    rope+phi on K, multiplies by V (staged through LDS), and atomically
//    accumulates KV/Ksum -- no C write at all. Replaces k_kvred.
template <bool BF16_OUT, bool FUSE>
__global__ __launch_bounds__(512, 2) void k_gemm256(const unsigned short* __restrict__ A,
    const unsigned short* __restrict__ Bw, void* __restrict__ Cv, int ldc,
    const float2* __restrict__ rope, float* __restrict__ KV, float* __restrict__ Ksum) {
  constexpr int K = DIMK;
  extern __shared__ __align__(16) unsigned short smem[];
  unsigned short* const AsP = smem;            // [2][16384] shorts (64 KiB)
  unsigned short* const BsP = smem + 32768;    // [2][16384] shorts (64 KiB)

  const int tid = threadIdx.x;
  const int wave = tid >> 6, lane = tid & 63;
  const int r = lane & 15, quad = lane >> 4, r7 = r & 7;
  const int wm = (wave >> 2) * 128, wn = (wave & 3) * 64;

  // XCD remap: bid -> (xcd = bid&7, j = bid>>3); within an XCD, n fastest.
  const int ngy = gridDim.y;
  const int bid = blockIdx.x + gridDim.x * blockIdx.y;
  const int xcd = bid & 7;
  const int j = bid >> 3;
  const int lg = (ngy == 4) ? 2 : 1;
  const int per = (gridDim.x * ngy) >> (3 + lg);   // m-tiles per XCD (=16)
  const int mt = xcd * per + (j >> lg);
  const int nt = j & (ngy - 1);
  const int m0 = mt * 256, n0 = nt * 256;

  // staging source (pre-swizzled): lane covers row (lane>>3), col-block (lane&7)^(row&7)
  const int srow = lane >> 3;
  const int scb = (lane & 7) ^ srow;
  const unsigned short* const Asrc = A + (size_t)(m0 + wave * 8 + srow) * K + scb * 8;
  const unsigned short* const Bsrc = Bw + (size_t)(n0 + wave * 8 + srow) * K + scb * 8;
  unsigned short* const Adst = AsP + wave * 8 * 64;  // + buf*16384 + rowoff*64
  unsigned short* const Bdst = BsP + wave * 8 * 64;

#define STAGE_A(buf, h, kt) do { \
    gload_lds16(Asrc + (size_t)((h) * 128) * K + (kt) * 64, Adst + (buf) * 16384 + ((h) * 128) * 64); \
    gload_lds16(Asrc + (size_t)((h) * 128 + 64) * K + (kt) * 64, Adst + (buf) * 16384 + ((h) * 128 + 64) * 64); \
  } while (0)
#define STAGE_B(buf, h, kt) do { \
    gload_lds16(Bsrc + (size_t)((h) * 128) * K + (kt) * 64, Bdst + (buf) * 16384 + ((h) * 128) * 64); \
    gload_lds16(Bsrc + (size_t)((h) * 128 + 64) * K + (kt) * 64, Bdst + (buf) * 16384 + ((h) * 128 + 64) * 64); \
  } while (0)

  short8 af[4][2], b0[2][2], b1[2][2];
  floatx4 acc[8][4];
  #pragma unroll
  for (int i = 0; i < 8; i++)
    #pragma unroll
    for (int jj = 0; jj < 4; jj++)
      acc[i][jj] = (floatx4){0.f, 0.f, 0.f, 0.f};

#define LDA8(buf, ah) do { \
    _Pragma("unroll") for (int ii = 0; ii < 4; ii++) \
      _Pragma("unroll") for (int kk = 0; kk < 2; kk++) \
        af[ii][kk] = *(const short8*)&AsP[(buf) * 16384 + (wm + (ah) * 64 + ii * 16 + r) * 64 + ((kk * 4 + quad) ^ r7) * 8]; \
  } while (0)
#define LDB4(buf, bh, arr) do { \
    _Pragma("unroll") for (int jj = 0; jj < 2; jj++) \
      _Pragma("unroll") for (int kk = 0; kk < 2; kk++) \
        arr[jj][kk] = *(const short8*)&BsP[(buf) * 16384 + (wn + (bh) * 32 + jj * 16 + r) * 64 + ((kk * 4 + quad) ^ r7) * 8]; \
  } while (0)
#define MFMAQ(ah, bh, arr) do { \
    __builtin_amdgcn_s_setprio(1); \
    _Pragma("unroll") for (int ii = 0; ii < 4; ii++) \
      _Pragma("unroll") for (int jj = 0; jj < 2; jj++) \
        _Pragma("unroll") for (int kk = 0; kk < 2; kk++) \
          acc[(ah) * 4 + ii][(bh) * 2 + jj] = __builtin_amdgcn_mfma_f32_16x16x32_bf16( \
              af[ii][kk], arr[jj][kk], acc[(ah) * 4 + ii][(bh) * 2 + jj], 0, 0, 0); \
    __builtin_amdgcn_s_setprio(0); \
  } while (0)
#define BAR() do { asm volatile("" ::: "memory"); __builtin_amdgcn_s_barrier(); asm volatile("" ::: "memory"); } while (0)
#define VMW(n) do { asm volatile("s_waitcnt vmcnt(" #n ")" ::: "memory"); __builtin_amdgcn_sched_barrier(0); } while (0)

  // ---- prologue: kt0 -> buf0 (8 loads), kt1 -> buf1 (8 loads); wait for kt0
  STAGE_A(0, 0, 0); STAGE_B(0, 0, 0); STAGE_A(0, 1, 0); STAGE_B(0, 1, 0);
  STAGE_A(1, 0, 1); STAGE_B(1, 0, 1); STAGE_A(1, 1, 1); STAGE_B(1, 1, 1);
  VMW(8);
  BAR();

  // ---- main: iterations over K-tile pairs (kt, kt+1); kt even->buf0, odd->buf1
  #pragma unroll
  for (int it = 0; it < 3; ++it) {
    const int kt = it * 2;
    // P1: quadrant (Ah0,Bh0) of kt
    LDA8(0, 0); LDB4(0, 0, b0);
    BAR(); MFMAQ(0, 0, b0); BAR();
    // P2: (Ah0,Bh1)
    LDB4(0, 1, b1);
    BAR(); MFMAQ(0, 1, b1); BAR();
    // P3: (Ah1,Bh1); B-buf0 fully read -> stage B-buf0(kt+2)
    LDA8(0, 1); STAGE_B(0, 0, kt + 2); STAGE_B(0, 1, kt + 2);
    BAR(); MFMAQ(1, 1, b1); BAR();
    // P4: (Ah1,Bh0) regs-only; A-buf0 fully read -> stage A-buf0(kt+2)
    STAGE_A(0, 0, kt + 2); STAGE_A(0, 1, kt + 2);
    BAR(); MFMAQ(1, 0, b0); VMW(8); BAR();
    // P5: quadrant (Ah0,Bh0) of kt+1
    LDA8(1, 0); LDB4(1, 0, b0);
    BAR(); MFMAQ(0, 0, b0); BAR();
    // P6
    LDB4(1, 1, b1);
    BAR(); MFMAQ(0, 1, b1); BAR();
    // P7: B-buf1 fully read -> stage B-buf1(kt+3)
    LDA8(1, 1); STAGE_B(1, 0, kt + 3); STAGE_B(1, 1, kt + 3);
    BAR(); MFMAQ(1, 1, b1); BAR();
    // P8: A-buf1 fully read -> stage A-buf1(kt+3)
    STAGE_A(1, 0, kt + 3); STAGE_A(1, 1, kt + 3);
    BAR(); MFMAQ(1, 0, b0); VMW(8); BAR();
  }

  // ---- epilogue: kt=6 (buf0), kt=7 (buf1); nothing left to stage
  LDA8(0, 0); LDB4(0, 0, b0);
  BAR(); MFMAQ(0, 0, b0); BAR();
  LDB4(0, 1, b1);
  BAR(); MFMAQ(0, 1, b1); BAR();
  LDA8(0, 1);
  BAR(); MFMAQ(1, 1, b1); BAR();
  MFMAQ(1, 0, b0); VMW(0); BAR();
  LDA8(1, 0); LDB4(1, 0, b0);
  BAR(); MFMAQ(0, 0, b0); BAR();
  LDB4(1, 1, b1);
  BAR(); MFMAQ(0, 1, b1); BAR();
  LDA8(1, 1);
  BAR(); MFMAQ(1, 1, b1); BAR();
  MFMAQ(1, 0, b0);

  if (FUSE && n0 >= 512) {
    // ---- fused KV/Ksum epilogue. acc cols (wn groups): 0=K_h, 64=V_h,
    // 128=K_{h+1}, 192=V_{h+1}. V-waves stage acc to LDS; K-waves rope+phi
    // their acc, multiply by V, reduce over the block's 256 tokens, atomic.
    const int b = m0 >> 13;
    const int kh = ((n0 - 512) >> 8) * 2 + (wn >> 7);   // n-tile is 256 wide (>>8!)
    const int hvb = (wn >> 7) << 6;            // V col base in Vs (0 or 64)
    float* const Vs = (float*)smem;            // [256][128] f32 = 128 KiB
    __syncthreads();                           // all LDS/MFMA reads done
    if (wn & 64) {                             // V-wave: dump acc to LDS
      #pragma unroll
      for (int i = 0; i < 8; i++)
        #pragma unroll
        for (int j2 = 0; j2 < 4; j2++)
          #pragma unroll
          for (int p = 0; p < 4; p++) {
            int t = wm + i * 16 + quad * 4 + p;
            Vs[t * 128 + hvb + j2 * 16 + r] = acc[i][j2][p];
          }
    }
    __syncthreads();
    if (!(wn & 64)) {                          // K-wave
      float kvp[4] = {0.f, 0.f, 0.f, 0.f};
      float ksp[4] = {0.f, 0.f, 0.f, 0.f};
      #pragma unroll
      for (int i = 0; i < 8; i++)
        #pragma unroll
        for (int p = 0; p < 4; p++) {
          int t = wm + i * 16 + quad * 4 + p;
          int pos = (m0 + t) & 8191;
          #pragma unroll
          for (int j2 = 0; j2 < 4; j2++) {
            float v = acc[i][j2][p];
            float vp = __shfl_xor(v, 1, 64);
            int d = j2 * 16 + r;
            float2 cs = rope[pos * 32 + (d >> 1)];
            float rk = (r & 1) ? (vp * cs.y + v * cs.x) : (v * cs.x - vp * cs.y);
            rk = rk > 0.f ? rk + 1.f : __expf(rk);
            kvp[j2] += rk * Vs[t * 128 + hvb + d];
            ksp[j2] += rk;
          }
        }
      #pragma unroll
      for (int j2 = 0; j2 < 4; j2++) {
        kvp[j2] += __shfl_xor(kvp[j2], 16, 64); kvp[j2] += __shfl_xor(kvp[j2], 32, 64);
        ksp[j2] += __shfl_xor(ksp[j2], 16, 64); ksp[j2] += __shfl_xor(ksp[j2], 32, 64);
      }
      if (lane < 16) {
        int base = (b * 4 + kh) * 64 + r;
        #pragma unroll
        for (int j2 = 0; j2 < 4; j2++) {
          atomicAdd(&KV[base + j2 * 16], kvp[j2]);
          atomicAdd(&Ksum[base + j2 * 16], ksp[j2]);
        }
      }
    }
  } else {
    // ---- C write. C/D layout: col = lane&15, row = quad*4 + p
    #pragma unroll
    for (int i = 0; i < 8; i++)
      #pragma unroll
      for (int j2 = 0; j2 < 4; j2++) {
        int row = m0 + wm + i * 16 + quad * 4;
        int col = n0 + wn + j2 * 16 + r;
        #pragma unroll
        for (int p = 0; p < 4; p++) {
          if constexpr (BF16_OUT) {
            ((unsigned short*)Cv)[(size_t)(row + p) * ldc + col] = f2bf(acc[i][j2][p]);
          } else {
            ((float*)Cv)[(size_t)(row + p) * ldc + col] = acc[i][j2][p];
          }
        }
      }
  }
#undef STAGE_A
#undef STAGE_B
#undef LDA8
#undef LDB4
#undef MFMAQ
#undef BAR
#undef VMW
}

// ------- Q path: half-wave (32 lanes) per head, one uint pair per lane -------
__global__ __launch_bounds__(256) void k_qkern(const unsigned short* __restrict__ qkv,
    const float2* __restrict__ rope, const float* __restrict__ KV,
    const float* __restrict__ Ksum, unsigned short* __restrict__ Yb) {
  const int h = threadIdx.x >> 5;   // head 0..7
  const int pr = threadIdx.x & 31;  // rotation pair 0..31
  for (int t = blockIdx.x; t < T_TOK; t += gridDim.x) {
    int b = t >> 13, pos = t & 8191;
    unsigned int qp = *(const unsigned int*)(qkv + (size_t)t * 512 + h * 64 + 2 * pr);
    float qx = bf2f((unsigned short)(qp & 0xffffu));
    float qy = bf2f((unsigned short)(qp >> 16));
    float2 cs = rope[pos * 32 + pr];
    float ar = qx * cs.x - qy * cs.y;
    float ai = qx * cs.y + qy * cs.x;
    ar = ar > 0.f ? ar + 1.f : __expf(ar);
    ai = ai > 0.f ? ai + 1.f : __expf(ai);
    int bk = b * 4 + (h >> 1);
    float2 ks = *(const float2*)(Ksum + bk * 64 + 2 * pr);
    float z = ar * ks.x + ai * ks.y;
    #pragma unroll
    for (int off = 16; off >= 1; off >>= 1) z += __shfl_xor(z, off, 64);  // stays in half-wave
    float2 kv = *(const float2*)(KV + bk * 64 + 2 * pr);
    float inv = 1.0f / (z + 1e-6f);
    unsigned int o = (unsigned int)f2bf(ar * kv.x * inv)
                   | ((unsigned int)f2bf(ai * kv.y * inv) << 16);
    *(unsigned int*)(Yb + (size_t)t * 512 + h * 64 + 2 * pr) = o;
  }
}

extern "C" void kernel_launch(void* const* d_in, const int* in_sizes, int n_in,
                              void* d_out, int out_size, void* d_ws, size_t ws_size,
                              hipStream_t stream) {
  const float* x = (const float*)d_in[0];
  const float* norm_w = (const float*)d_in[1];
  const float* wq = (const float*)d_in[2];
  const float* wk = (const float*)d_in[3];
  const float* wv = (const float*)d_in[4];
  const float* wo = (const float*)d_in[5];
  float* out = (float*)d_out;

  char* ws = (char*)d_ws;
  unsigned short* xn  = (unsigned short*)(ws);                  // 33,554,432 B
  unsigned short* Wb  = (unsigned short*)(ws + 33554432);       //  1,048,576 B
  unsigned short* wob = (unsigned short*)(ws + 34603008);       //    524,288 B
  unsigned short* qkv = (unsigned short*)(ws + 35127296);       // 33,554,432 B (Q only, stride 512)
  float2* rope        = (float2*)(ws + 102236160);              //  2,097,152 B
  float* KV           = (float*)(ws + 104333312);               //      4,096 B
  float* Ksum         = (float*)(ws + 104337408);               //      4,096 B
  unsigned short* Yb  = (unsigned short*)(ws + 104341504);      // 33,554,432 B

  static bool s_attr = false;
  if (!s_attr) {
    (void)hipFuncSetAttribute(reinterpret_cast<const void*>(&k_gemm256<true, true>),
                              hipFuncAttributeMaxDynamicSharedMemorySize, 131072);
    (void)hipFuncSetAttribute(reinterpret_cast<const void*>(&k_gemm256<false, false>),
                              hipFuncAttributeMaxDynamicSharedMemorySize, 131072);
    s_attr = true;
  }

  k_prep<<<10240, 256, 0, stream>>>(x, norm_w, wq, wk, wv, wo, Wb, wob, rope, KV, xn);
  k_gemm256<true, true><<<dim3(128, 4), 512, 131072, stream>>>(
      xn, Wb, (void*)qkv, 512, rope, KV, Ksum);
  k_qkern<<<4096, 256, 0, stream>>>(qkv, rope, KV, Ksum, Yb);
  k_gemm256<false, false><<<dim3(128, 2), 512, 131072, stream>>>(
      Yb, wob, (void*)out, 512, nullptr, nullptr, nullptr);
}

// Round 5
// 219.289 us; speedup vs baseline: 1.0675x; 1.0046x over previous
//
#include <hip/hip_runtime.h>
#include <cmath>

typedef __attribute__((ext_vector_type(8))) short short8;
typedef __attribute__((ext_vector_type(4))) float floatx4;

#define T_TOK 32768
#define DIMK 512
#define AKT 2097152  // 32768*64 shorts: A K-tile stride (both GEMMs have M=32768)

__device__ __forceinline__ unsigned short f2bf(float f) {
  union { float f; unsigned int u; } v; v.f = f;
  unsigned int r = (v.u + 0x7fffu + ((v.u >> 16) & 1u)) >> 16;
  return (unsigned short)r;
}
__device__ __forceinline__ float bf2f(unsigned short h) {
  union { unsigned int u; float f; } v; v.u = ((unsigned int)h) << 16;
  return v.f;
}

// async global->LDS 16B per lane: HW writes lane i at ldsbase + i*16
__device__ __forceinline__ void gload_lds16(const unsigned short* g, unsigned short* ldsbase) {
  __builtin_amdgcn_global_load_lds(
      (const __attribute__((address_space(1))) unsigned int*)g,
      (__attribute__((address_space(3))) unsigned int*)ldsbase, 16, 0, 0);
}

// ------- prep: [blocks 0..2047] weights->bf16 (K-TILED) + rope + zero; [2048..10239] rmsnorm -------
// All GEMM operands stored K-tiled: X_t[kt][row][64] so one K-tile slab is
// contiguous -> global_load_lds staging is fully coalesced (1KB per instr).
// Wb logical rows: 0..511 = wq rows; rows 512..1023 interleaved per KV head:
//   row 512+h*128+d <- wk[h*64+d], row 512+h*128+64+d <- wv[h*64+d].
__global__ __launch_bounds__(256) void k_prep(const float* __restrict__ x,
    const float* __restrict__ norm_w, const float* __restrict__ wq,
    const float* __restrict__ wk, const float* __restrict__ wv,
    const float* __restrict__ wo, unsigned short* __restrict__ Wb,
    unsigned short* __restrict__ wob, float2* __restrict__ rope,
    float* __restrict__ KVz, unsigned short* __restrict__ xn) {
  if (blockIdx.x < 2048) {
    int i = blockIdx.x * 256 + threadIdx.x;  // 524288
    int R = i >> 9, col = i & 511;
    float v;
    if (i < 262144) {
      v = wq[i];
    } else {
      int h = (R - 512) >> 7, rem = (R - 512) & 127;
      if (rem < 64) v = wk[(h * 64 + rem) * 512 + col];
      else          v = wv[(h * 64 + rem - 64) * 512 + col];
    }
    // K-tiled write: Wb_t[col>>6][R][col&63], N=1024 rows -> kt stride 65536
    Wb[(col >> 6) * 65536 + R * 64 + (col & 63)] = f2bf(v);
    if (i < 262144) {
      // wob K-tiled: N=512 rows -> kt stride 32768
      wob[(col >> 6) * 32768 + R * 64 + (col & 63)] = f2bf(wo[i]);
      int s = i >> 5, m = i & 31;
      const double c0 = 0.74989420933245582;   // 10^(-1/8)
      double c1 = c0 * c0, c2 = c1 * c1, c3 = c2 * c2, c4 = c3 * c3;
      double p = 1.0;
      if (m & 1)  p *= c0;
      if (m & 2)  p *= c1;
      if (m & 4)  p *= c2;
      if (m & 8)  p *= c3;
      if (m & 16) p *= c4;
      double ang = (double)s * p;
      const double TWO_PI = 6.2831853071795864769;
      double q = rint(ang * (1.0 / TWO_PI));
      double r = fma(-q, TWO_PI, ang);
      float rf = (float)r;
      rope[i] = make_float2(cosf(rf), sinf(rf));
    }
    if (i < 2048) KVz[i] = 0.f;   // zero KV (1024 f32) + Ksum (1024 f32)
  } else {
    int bid = blockIdx.x - 2048;
    int wave = threadIdx.x >> 6, lane = threadIdx.x & 63;
    size_t t = (size_t)bid * 4 + wave;
    const float4* xr = (const float4*)(x + t * DIMK);
    float4 a = xr[lane * 2];
    float4 b = xr[lane * 2 + 1];
    float ss = a.x * a.x + a.y * a.y + a.z * a.z + a.w * a.w
             + b.x * b.x + b.y * b.y + b.z * b.z + b.w * b.w;
    #pragma unroll
    for (int off = 32; off >= 1; off >>= 1) ss += __shfl_xor(ss, off, 64);
    float scale = rsqrtf(ss * (1.0f / DIMK) + 1e-6f);
    const float4* wr = (const float4*)norm_w;
    float4 w0 = wr[lane * 2], w1 = wr[lane * 2 + 1];
    uint4 o;
    o.x = (unsigned int)f2bf(a.x * scale * w0.x) | ((unsigned int)f2bf(a.y * scale * w0.y) << 16);
    o.y = (unsigned int)f2bf(a.z * scale * w0.z) | ((unsigned int)f2bf(a.w * scale * w0.w) << 16);
    o.z = (unsigned int)f2bf(b.x * scale * w1.x) | ((unsigned int)f2bf(b.y * scale * w1.y) << 16);
    o.w = (unsigned int)f2bf(b.z * scale * w1.z) | ((unsigned int)f2bf(b.w * scale * w1.w) << 16);
    // K-tiled write: xn_t[lane>>3][t][(lane&7)*8], kt stride = 32768*64
    *(uint4*)(xn + (size_t)(lane >> 3) * AKT + t * 64 + (lane & 7) * 8) = o;
  }
}

// ------- GEMM: C(M,N) = A(M,512) * Bw(N,512)^T, operands K-TILED -------
// 256x256 tile, BK=64, 8 waves, 8-phase counted-vmcnt schedule (verified r2),
// XCD remap for A-reuse (verified r4: FETCH 67.7->28.1MB), FUSE epilogue (r4).
// NEW r5: operands K-tiled -> each gload_lds16 reads a contiguous 1KB slab
// (coalesced; previously 64 lanes scattered at 1KB row stride). LDS layout
// and swizzle involution unchanged. Fused Vs access group-rotated by t>>2
// to turn the 4-way bank conflict into a free 2-way.
template <bool BF16_OUT, bool FUSE>
__global__ __launch_bounds__(512, 2) void k_gemm256(const unsigned short* __restrict__ A,
    const unsigned short* __restrict__ Bw, void* __restrict__ Cv, int ldc, int nrows,
    const float2* __restrict__ rope, float* __restrict__ KV, float* __restrict__ Ksum) {
  extern __shared__ __align__(16) unsigned short smem[];
  unsigned short* const AsP = smem;            // [2][16384] shorts (64 KiB)
  unsigned short* const BsP = smem + 32768;    // [2][16384] shorts (64 KiB)

  const int tid = threadIdx.x;
  const int wave = tid >> 6, lane = tid & 63;
  const int r = lane & 15, quad = lane >> 4, r7 = r & 7;
  const int wm = (wave >> 2) * 128, wn = (wave & 3) * 64;

  // XCD remap: bid -> (xcd = bid&7, j = bid>>3); within an XCD, n fastest.
  const int ngy = gridDim.y;
  const int bid = blockIdx.x + gridDim.x * blockIdx.y;
  const int xcd = bid & 7;
  const int j = bid >> 3;
  const int lg = (ngy == 4) ? 2 : 1;
  const int per = (gridDim.x * ngy) >> (3 + lg);   // m-tiles per XCD (=16)
  const int mt = xcd * per + (j >> lg);
  const int nt = j & (ngy - 1);
  const int m0 = mt * 256, n0 = nt * 256;

  // staging source (pre-swizzled within the contiguous 1KB slab):
  // lane covers row (lane>>3), col-block (lane&7)^(row&7)
  const int srow = lane >> 3;
  const int scb = (lane & 7) ^ srow;
  const size_t bkt = (size_t)nrows * 64;           // B K-tile stride (shorts)
  const unsigned short* const Asrc = A + (size_t)(m0 + wave * 8 + srow) * 64 + scb * 8;
  const unsigned short* const Bsrc = Bw + (size_t)(n0 + wave * 8 + srow) * 64 + scb * 8;
  unsigned short* const Adst = AsP + wave * 8 * 64;  // + buf*16384 + rowoff*64
  unsigned short* const Bdst = BsP + wave * 8 * 64;

#define STAGE_A(buf, h, kt) do { \
    gload_lds16(Asrc + (size_t)(kt) * AKT + (h) * 8192, Adst + (buf) * 16384 + ((h) * 128) * 64); \
    gload_lds16(Asrc + (size_t)(kt) * AKT + (h) * 8192 + 4096, Adst + (buf) * 16384 + ((h) * 128 + 64) * 64); \
  } while (0)
#define STAGE_B(buf, h, kt) do { \
    gload_lds16(Bsrc + (size_t)(kt) * bkt + (h) * 8192, Bdst + (buf) * 16384 + ((h) * 128) * 64); \
    gload_lds16(Bsrc + (size_t)(kt) * bkt + (h) * 8192 + 4096, Bdst + (buf) * 16384 + ((h) * 128 + 64) * 64); \
  } while (0)

  short8 af[4][2], b0[2][2], b1[2][2];
  floatx4 acc[8][4];
  #pragma unroll
  for (int i = 0; i < 8; i++)
    #pragma unroll
    for (int jj = 0; jj < 4; jj++)
      acc[i][jj] = (floatx4){0.f, 0.f, 0.f, 0.f};

#define LDA8(buf, ah) do { \
    _Pragma("unroll") for (int ii = 0; ii < 4; ii++) \
      _Pragma("unroll") for (int kk = 0; kk < 2; kk++) \
        af[ii][kk] = *(const short8*)&AsP[(buf) * 16384 + (wm + (ah) * 64 + ii * 16 + r) * 64 + ((kk * 4 + quad) ^ r7) * 8]; \
  } while (0)
#define LDB4(buf, bh, arr) do { \
    _Pragma("unroll") for (int jj = 0; jj < 2; jj++) \
      _Pragma("unroll") for (int kk = 0; kk < 2; kk++) \
        arr[jj][kk] = *(const short8*)&BsP[(buf) * 16384 + (wn + (bh) * 32 + jj * 16 + r) * 64 + ((kk * 4 + quad) ^ r7) * 8]; \
  } while (0)
#define MFMAQ(ah, bh, arr) do { \
    __builtin_amdgcn_s_setprio(1); \
    _Pragma("unroll") for (int ii = 0; ii < 4; ii++) \
      _Pragma("unroll") for (int jj = 0; jj < 2; jj++) \
        _Pragma("unroll") for (int kk = 0; kk < 2; kk++) \
          acc[(ah) * 4 + ii][(bh) * 2 + jj] = __builtin_amdgcn_mfma_f32_16x16x32_bf16( \
              af[ii][kk], arr[jj][kk], acc[(ah) * 4 + ii][(bh) * 2 + jj], 0, 0, 0); \
    __builtin_amdgcn_s_setprio(0); \
  } while (0)
#define BAR() do { asm volatile("" ::: "memory"); __builtin_amdgcn_s_barrier(); asm volatile("" ::: "memory"); } while (0)
#define VMW(n) do { asm volatile("s_waitcnt vmcnt(" #n ")" ::: "memory"); __builtin_amdgcn_sched_barrier(0); } while (0)

  // ---- prologue: kt0 -> buf0 (8 loads), kt1 -> buf1 (8 loads); wait for kt0
  STAGE_A(0, 0, 0); STAGE_B(0, 0, 0); STAGE_A(0, 1, 0); STAGE_B(0, 1, 0);
  STAGE_A(1, 0, 1); STAGE_B(1, 0, 1); STAGE_A(1, 1, 1); STAGE_B(1, 1, 1);
  VMW(8);
  BAR();

  // ---- main: iterations over K-tile pairs (kt, kt+1); kt even->buf0, odd->buf1
  #pragma unroll
  for (int it = 0; it < 3; ++it) {
    const int kt = it * 2;
    // P1: quadrant (Ah0,Bh0) of kt
    LDA8(0, 0); LDB4(0, 0, b0);
    BAR(); MFMAQ(0, 0, b0); BAR();
    // P2: (Ah0,Bh1)
    LDB4(0, 1, b1);
    BAR(); MFMAQ(0, 1, b1); BAR();
    // P3: (Ah1,Bh1); B-buf0 fully read -> stage B-buf0(kt+2)
    LDA8(0, 1); STAGE_B(0, 0, kt + 2); STAGE_B(0, 1, kt + 2);
    BAR(); MFMAQ(1, 1, b1); BAR();
    // P4: (Ah1,Bh0) regs-only; A-buf0 fully read -> stage A-buf0(kt+2)
    STAGE_A(0, 0, kt + 2); STAGE_A(0, 1, kt + 2);
    BAR(); MFMAQ(1, 0, b0); VMW(8); BAR();
    // P5: quadrant (Ah0,Bh0) of kt+1
    LDA8(1, 0); LDB4(1, 0, b0);
    BAR(); MFMAQ(0, 0, b0); BAR();
    // P6
    LDB4(1, 1, b1);
    BAR(); MFMAQ(0, 1, b1); BAR();
    // P7: B-buf1 fully read -> stage B-buf1(kt+3)
    LDA8(1, 1); STAGE_B(1, 0, kt + 3); STAGE_B(1, 1, kt + 3);
    BAR(); MFMAQ(1, 1, b1); BAR();
    // P8: A-buf1 fully read -> stage A-buf1(kt+3)
    STAGE_A(1, 0, kt + 3); STAGE_A(1, 1, kt + 3);
    BAR(); MFMAQ(1, 0, b0); VMW(8); BAR();
  }

  // ---- epilogue: kt=6 (buf0), kt=7 (buf1); nothing left to stage
  LDA8(0, 0); LDB4(0, 0, b0);
  BAR(); MFMAQ(0, 0, b0); BAR();
  LDB4(0, 1, b1);
  BAR(); MFMAQ(0, 1, b1); BAR();
  LDA8(0, 1);
  BAR(); MFMAQ(1, 1, b1); BAR();
  MFMAQ(1, 0, b0); VMW(0); BAR();
  LDA8(1, 0); LDB4(1, 0, b0);
  BAR(); MFMAQ(0, 0, b0); BAR();
  LDB4(1, 1, b1);
  BAR(); MFMAQ(0, 1, b1); BAR();
  LDA8(1, 1);
  BAR(); MFMAQ(1, 1, b1); BAR();
  MFMAQ(1, 0, b0);

  if (FUSE && n0 >= 512) {
    // ---- fused KV/Ksum epilogue. acc cols (wn groups): 0=K_h, 64=V_h,
    // 128=K_{h+1}, 192=V_{h+1}. V-waves stage acc to LDS; K-waves rope+phi
    // their acc, multiply by V, reduce over the block's 256 tokens, atomic.
    // Vs index group-rotated by (t>>2): 2-way bank access (free) vs 4-way.
#define VSW(t, d) ((t) * 128 + ((d) & 15) + (((((d) >> 4) + ((t) >> 2)) & 7) << 4))
    const int b = m0 >> 13;
    const int kh = ((n0 - 512) >> 8) * 2 + (wn >> 7);   // n-tile is 256 wide
    const int hvb = (wn >> 7) << 6;            // V col base in Vs (0 or 64)
    float* const Vs = (float*)smem;            // [256][128] f32 = 128 KiB
    __syncthreads();                           // all LDS/MFMA reads done
    if (wn & 64) {                             // V-wave: dump acc to LDS
      #pragma unroll
      for (int i = 0; i < 8; i++)
        #pragma unroll
        for (int j2 = 0; j2 < 4; j2++)
          #pragma unroll
          for (int p = 0; p < 4; p++) {
            int t = wm + i * 16 + quad * 4 + p;
            Vs[VSW(t, hvb + j2 * 16 + r)] = acc[i][j2][p];
          }
    }
    __syncthreads();
    if (!(wn & 64)) {                          // K-wave
      float kvp[4] = {0.f, 0.f, 0.f, 0.f};
      float ksp[4] = {0.f, 0.f, 0.f, 0.f};
      #pragma unroll
      for (int i = 0; i < 8; i++)
        #pragma unroll
        for (int p = 0; p < 4; p++) {
          int t = wm + i * 16 + quad * 4 + p;
          int pos = (m0 + t) & 8191;
          #pragma unroll
          for (int j2 = 0; j2 < 4; j2++) {
            float v = acc[i][j2][p];
            float vp = __shfl_xor(v, 1, 64);
            int d = j2 * 16 + r;
            float2 cs = rope[pos * 32 + (d >> 1)];
            float rk = (r & 1) ? (vp * cs.y + v * cs.x) : (v * cs.x - vp * cs.y);
            rk = rk > 0.f ? rk + 1.f : __expf(rk);
            kvp[j2] += rk * Vs[VSW(t, hvb + d)];
            ksp[j2] += rk;
          }
        }
      #pragma unroll
      for (int j2 = 0; j2 < 4; j2++) {
        kvp[j2] += __shfl_xor(kvp[j2], 16, 64); kvp[j2] += __shfl_xor(kvp[j2], 32, 64);
        ksp[j2] += __shfl_xor(ksp[j2], 16, 64); ksp[j2] += __shfl_xor(ksp[j2], 32, 64);
      }
      if (lane < 16) {
        int base = (b * 4 + kh) * 64 + r;
        #pragma unroll
        for (int j2 = 0; j2 < 4; j2++) {
          atomicAdd(&KV[base + j2 * 16], kvp[j2]);
          atomicAdd(&Ksum[base + j2 * 16], ksp[j2]);
        }
      }
    }
#undef VSW
  } else {
    // ---- C write (row-major). C/D layout: col = lane&15, row = quad*4 + p
    #pragma unroll
    for (int i = 0; i < 8; i++)
      #pragma unroll
      for (int j2 = 0; j2 < 4; j2++) {
        int row = m0 + wm + i * 16 + quad * 4;
        int col = n0 + wn + j2 * 16 + r;
        #pragma unroll
        for (int p = 0; p < 4; p++) {
          if constexpr (BF16_OUT) {
            ((unsigned short*)Cv)[(size_t)(row + p) * ldc + col] = f2bf(acc[i][j2][p]);
          } else {
            ((float*)Cv)[(size_t)(row + p) * ldc + col] = acc[i][j2][p];
          }
        }
      }
  }
#undef STAGE_A
#undef STAGE_B
#undef LDA8
#undef LDB4
#undef MFMAQ
#undef BAR
#undef VMW
}

// ------- Q path: half-wave (32 lanes) per head, one uint pair per lane -------
// Reads qkv row-major (GEMM1's Q C-write); writes Yb K-TILED for GEMM2 staging.
__global__ __launch_bounds__(256) void k_qkern(const unsigned short* __restrict__ qkv,
    const float2* __restrict__ rope, const float* __restrict__ KV,
    const float* __restrict__ Ksum, unsigned short* __restrict__ Yb) {
  const int h = threadIdx.x >> 5;   // head 0..7
  const int pr = threadIdx.x & 31;  // rotation pair 0..31
  for (int t = blockIdx.x; t < T_TOK; t += gridDim.x) {
    int b = t >> 13, pos = t & 8191;
    unsigned int qp = *(const unsigned int*)(qkv + (size_t)t * 512 + h * 64 + 2 * pr);
    float qx = bf2f((unsigned short)(qp & 0xffffu));
    float qy = bf2f((unsigned short)(qp >> 16));
    float2 cs = rope[pos * 32 + pr];
    float ar = qx * cs.x - qy * cs.y;
    float ai = qx * cs.y + qy * cs.x;
    ar = ar > 0.f ? ar + 1.f : __expf(ar);
    ai = ai > 0.f ? ai + 1.f : __expf(ai);
    int bk = b * 4 + (h >> 1);
    float2 ks = *(const float2*)(Ksum + bk * 64 + 2 * pr);
    float z = ar * ks.x + ai * ks.y;
    #pragma unroll
    for (int off = 16; off >= 1; off >>= 1) z += __shfl_xor(z, off, 64);  // stays in half-wave
    float2 kv = *(const float2*)(KV + bk * 64 + 2 * pr);
    float inv = 1.0f / (z + 1e-6f);
    unsigned int o = (unsigned int)f2bf(ar * kv.x * inv)
                   | ((unsigned int)f2bf(ai * kv.y * inv) << 16);
    // K-tiled: head h's 64 dims are exactly K-tile h -> Yb_t[h][t][2*pr]
    *(unsigned int*)(Yb + (size_t)h * AKT + t * 64 + 2 * pr) = o;
  }
}

extern "C" void kernel_launch(void* const* d_in, const int* in_sizes, int n_in,
                              void* d_out, int out_size, void* d_ws, size_t ws_size,
                              hipStream_t stream) {
  const float* x = (const float*)d_in[0];
  const float* norm_w = (const float*)d_in[1];
  const float* wq = (const float*)d_in[2];
  const float* wk = (const float*)d_in[3];
  const float* wv = (const float*)d_in[4];
  const float* wo = (const float*)d_in[5];
  float* out = (float*)d_out;

  char* ws = (char*)d_ws;
  unsigned short* xn  = (unsigned short*)(ws);                  // 33,554,432 B (K-tiled)
  unsigned short* Wb  = (unsigned short*)(ws + 33554432);       //  1,048,576 B (K-tiled)
  unsigned short* wob = (unsigned short*)(ws + 34603008);       //    524,288 B (K-tiled)
  unsigned short* qkv = (unsigned short*)(ws + 35127296);       // 33,554,432 B (Q only, row-major)
  float2* rope        = (float2*)(ws + 102236160);              //  2,097,152 B
  float* KV           = (float*)(ws + 104333312);               //      4,096 B
  float* Ksum         = (float*)(ws + 104337408);               //      4,096 B
  unsigned short* Yb  = (unsigned short*)(ws + 104341504);      // 33,554,432 B (K-tiled)

  static bool s_attr = false;
  if (!s_attr) {
    (void)hipFuncSetAttribute(reinterpret_cast<const void*>(&k_gemm256<true, true>),
                              hipFuncAttributeMaxDynamicSharedMemorySize, 131072);
    (void)hipFuncSetAttribute(reinterpret_cast<const void*>(&k_gemm256<false, false>),
                              hipFuncAttributeMaxDynamicSharedMemorySize, 131072);
    s_attr = true;
  }

  k_prep<<<10240, 256, 0, stream>>>(x, norm_w, wq, wk, wv, wo, Wb, wob, rope, KV, xn);
  k_gemm256<true, true><<<dim3(128, 4), 512, 131072, stream>>>(
      xn, Wb, (void*)qkv, 512, 1024, rope, KV, Ksum);
  k_qkern<<<4096, 256, 0, stream>>>(qkv, rope, KV, Ksum, Yb);
  k_gemm256<false, false><<<dim3(128, 2), 512, 131072, stream>>>(
      Yb, wob, (void*)out, 512, 512, nullptr, nullptr, nullptr);
}